// Round 12
// baseline (288.795 us; speedup 1.0000x reference)
//
#include <hip/hip_runtime.h>

#define NQv   32768
#define GSH   9216            // shorts per staged weight group: 18 tiles x 512
#define NGRP  9
#define WTOT  (GSH*NGRP)      // 82,944 shorts of weight image (324 blocks exactly)
#define ASTR  104             // feats/hidden plane stride in shorts (208B)
#define CSTR  80              // coord plane stride in shorts
#define WBLK  325             // prep weight blocks (324 weight + badj tail in block 324)

typedef __attribute__((ext_vector_type(8))) short  short8;
typedef __attribute__((ext_vector_type(4))) float  float4v;
typedef __attribute__((ext_vector_type(2))) float  float2v;

__device__ __forceinline__ float bfu2f(unsigned short u) {
  return __uint_as_float(((unsigned int)u) << 16);
}
__device__ __forceinline__ unsigned short f2bfu(float f) {
  unsigned int x = __float_as_uint(f);
  x += 0x7fffu + ((x >> 16) & 1u);   // RNE
  return (unsigned short)(x >> 16);
}
// ties-away bf16 round, result in bits [31:16]
__device__ __forceinline__ unsigned int rnd16(float f) {
  return __float_as_uint(f) + 0x8000u;
}
// pack two floats -> (bf16(hi)<<16)|bf16(lo) in 3 VALU (prologue paths)
__device__ __forceinline__ unsigned int pkp(float lo, float hi) {
  return __builtin_amdgcn_perm(rnd16(hi), rnd16(lo), 0x07060302u);
}
// single-instruction packed bf16 convert (RNE), src0->low — epilogue hot path
__device__ __forceinline__ unsigned int pkbf(float lo, float hi) {
  unsigned int r;
  asm("v_cvt_pk_bf16_f32 %0, %1, %2" : "=v"(r) : "v"(lo), "v"(hi));
  return r;
}
__device__ __forceinline__ float silu_f(float x) {
  float e = __expf(-x);
  return x * __builtin_amdgcn_rcpf(1.f + e);
}
// packed-pair silu: muls/adds become v_pk_*_f32 (VOP3P), trans stay scalar.
// NOTE round-11 lesson: keep pairs INDEPENDENT (high ILP). The rcp-sharing
// product trick (silu4) lowered issue count but built a 10-deep serial chain
// and regressed 27% — epilogues are latency-sensitive at 2 waves/SIMD.
__device__ __forceinline__ float2v silu2(float2v x) {
  float2v t = x * -1.44269504088896341f;     // v_pk_mul_f32
  float2v e;
  e.x = __builtin_amdgcn_exp2f(t.x);
  e.y = __builtin_amdgcn_exp2f(t.y);
  float2v s = e + 1.f;                       // v_pk_add_f32
  float2v r;
  r.x = __builtin_amdgcn_rcpf(s.x);
  r.y = __builtin_amdgcn_rcpf(s.y);
  return x * r;                              // v_pk_mul_f32
}
__device__ __forceinline__ int clamp31(int v) { return min(max(v, 0), 31); }

// async global->LDS, 16B per lane; LDS dest must be wave-uniform base + lane*16
__device__ __forceinline__ void gload_lds16(const void* g, void* l) {
  typedef const __attribute__((address_space(1))) unsigned int GU;
  typedef __attribute__((address_space(3))) unsigned int LU;
  __builtin_amdgcn_global_load_lds((GU*)g, (LU*)l, 16, 0, 0);
}

// ---- fused pre-kernel ----
// blocks [0,WBLK): build the weight image in CHUNK-LINEAR tile layout:
//   group g = 18 tiles (T = mt*3+cb), tile = 64 chunks (c = ln15*4+quad) of 8
//   shorts: ws[g*GSH + T*512 + c*8 + e] = W_g[k = cb*32+quad*8+e][n = mt*16+ln15].
//   A wave's ds_read_b128 for (mt,cb) then reads 64 CONSECUTIVE 16B chunks.
//   Plus centered-coord adjusted biases (badj, f32) at ws+WTOT.
// blocks [WBLK, WBLK+1024): transpose ctxv [b][c][spat] f32 -> ctxvt [b][spat][c] bf16.
__global__ __launch_bounds__(256) void prep_kernel(
    const float* __restrict__ ctxv,
    const float* __restrict__ w00, const float* __restrict__ w01,
    const float* __restrict__ w02, const float* __restrict__ w10,
    const float* __restrict__ w11, const float* __restrict__ w12,
    const float* __restrict__ wpost,
    const float* __restrict__ b00, const float* __restrict__ b10,
    unsigned short* __restrict__ ws, unsigned short* __restrict__ ctxvt)
{
  __shared__ float tile[96][65];
  const int blk0 = blockIdx.x;
  const int t = threadIdx.x;
  if (blk0 < WBLK) {
    int e = blk0 * 256 + t;
    if (e >= WTOT) {
      // badj: b' = b + 15.5*sum_{k=96..101} W[k][ch]  (coords centered by 15.5)
      int e2 = e - WTOT;
      if (e2 < 192) {
        int mat = e2 / 96, ch = e2 - mat * 96;
        const float* w = mat ? w10 : w00;
        const float* bb = mat ? b10 : b00;
        float s = bb[ch];
#pragma unroll
        for (int k = 0; k < 6; ++k) s += 15.5f * w[(96 + k) * 96 + ch];
        ((float*)(ws + WTOT))[e2] = s;
      }
      return;
    }
    int g = e / GSH, r = e - g * GSH;
    int T = r >> 9, c = (r >> 3) & 63, e8 = r & 7;
    int mt = T / 3, cb = T - mt * 3;
    int ln15 = c >> 2, quad = c & 3;
    int n = mt * 16 + ln15;
    int kk = cb * 32 + quad * 8 + e8;        // 0..95
    const float* src; int Ksrc, Nsrc, kofs;
    switch (g) {
      case 0:  src = w00;   Ksrc = 174; Nsrc = 96; kofs = 0;  break;
      case 1:  src = w00;   Ksrc = 174; Nsrc = 96; kofs = 96; break;
      case 2:  src = w01;   Ksrc = 96;  Nsrc = 96; kofs = 0;  break;
      case 3:  src = w02;   Ksrc = 96;  Nsrc = 96; kofs = 0;  break;
      case 4:  src = w10;   Ksrc = 174; Nsrc = 96; kofs = 0;  break;
      case 5:  src = w10;   Ksrc = 174; Nsrc = 96; kofs = 96; break;
      case 6:  src = w11;   Ksrc = 96;  Nsrc = 96; kofs = 0;  break;
      case 7:  src = w12;   Ksrc = 96;  Nsrc = 96; kofs = 0;  break;
      default: src = wpost; Ksrc = 96;  Nsrc = 45; kofs = 0;  break;
    }
    int k = kofs + kk;
    float v = (k < Ksrc && n < Nsrc) ? src[k * Nsrc + n] : 0.f;
    ws[e] = f2bfu(v);
    return;
  }
  const int blk = blk0 - WBLK;              // 1024 = 2 batches * 512
  const int b = blk >> 9, s0 = (blk & 511) << 6;
  const int cq = t >> 6, sl = t & 63;
#pragma unroll
  for (int p = 0; p < 24; ++p) {
    int c = cq + p * 4;
    tile[c][sl] = ctxv[(((size_t)(b * 96 + c)) << 15) + s0 + sl];
  }
  __syncthreads();
#pragma unroll
  for (int i = 0; i < 24; ++i) {
    int u = t + 256 * i;
    int s = u / 96, c = u - s * 96;
    ctxvt[((size_t)(b << 15) + s0 + s) * 96 + c] = f2bfu(tile[c][s]);
  }
}

// ---- group GEMM: one staged weight group (96 outs x 96 k) from LDS sW
//      (chunk-linear tiles);
//      B either LDS plane rows rowb.. (stride ASTR) or register coord frags Bin.
//      s_setprio(1) around the MFMA block (T5): with 2 independent blocks/CU
//      at different phases, MFMA-entering waves get issue priority over the
//      other block's epilogue/stage waves. Pure arbitration hint, no semantics. ----
template<int NM, bool INIT, bool BREG>
__device__ __forceinline__ void run_group(
    const short* __restrict__ sWp,
    const short* pA, const short8 (&Bin)[3][2],
    const float* __restrict__ bias, int biasN,
    float4v (&C)[NM][2], int lane, int rowb)
{
  const int ln15 = lane & 15, quad = lane >> 4;
  const int cidx = ((ln15 << 2) | quad) << 3;    // chunk offset in shorts
  if (INIT) {
    if (biasN >= NM * 16) {
#pragma unroll
      for (int mt = 0; mt < NM; ++mt) {
        float4v bv = *(const float4v*)(bias + mt * 16 + quad * 4);
        C[mt][0] = bv; C[mt][1] = bv;
      }
    } else {
#pragma unroll
      for (int mt = 0; mt < NM; ++mt) {
        int c0 = mt * 16 + quad * 4;
        float4v bv;
#pragma unroll
        for (int r = 0; r < 4; ++r) bv[r] = (c0 + r < biasN) ? bias[c0 + r] : 0.f;
        C[mt][0] = bv; C[mt][1] = bv;
      }
    }
  }
  short8 Wh[3][NM];
#pragma unroll
  for (int cb = 0; cb < 3; ++cb)
#pragma unroll
    for (int mt = 0; mt < NM; ++mt)
      Wh[cb][mt] = *(const short8*)&sWp[((mt * 3 + cb) << 9) + cidx];
  short8 Bh[3][2];
  if (BREG) {
#pragma unroll
    for (int cb = 0; cb < 3; ++cb) {
      Bh[cb][0] = Bin[cb][0]; Bh[cb][1] = Bin[cb][1];
    }
  } else {
#pragma unroll
    for (int cb = 0; cb < 3; ++cb)
#pragma unroll
      for (int nt = 0; nt < 2; ++nt)
        Bh[cb][nt] = *(const short8*)&pA[(rowb + nt * 16 + ln15) * ASTR + cb * 32 + quad * 8];
  }
  __builtin_amdgcn_s_setprio(1);
#pragma unroll
  for (int cb = 0; cb < 3; ++cb)
#pragma unroll
    for (int mt = 0; mt < NM; ++mt)
#pragma unroll
      for (int nt = 0; nt < 2; ++nt)
        C[mt][nt] = __builtin_amdgcn_mfma_f32_16x16x32_bf16(Wh[cb][mt], Bh[cb][nt], C[mt][nt], 0, 0, 0);
  __builtin_amdgcn_s_setprio(0);
}

template<bool TRANSPOSED>
__global__ __launch_bounds__(256, 2) void decoder_kernel(
    const float* __restrict__ ctxv,            // [2,96,32768] f32
    const unsigned short* __restrict__ ctxvt,  // [2,32768,96] bf16 (in ws) or unused
    const float* __restrict__ qwc,     // [2,32768,3]
    const float* __restrict__ aff,     // [2,4,4]
    const float* __restrict__ b01, const float* __restrict__ b02,
    const float* __restrict__ b11, const float* __restrict__ b12,
    const float* __restrict__ bpost,
    const unsigned short* __restrict__ ws,
    float* __restrict__ out)           // [2,45,32768]
{
  // LDS: sY 26,624 + sH 26,624 + sW 18,432 = 71,680 B -> 2 blocks/CU.
  // 2 blocks/CU is load-bearing (round-8: 1 block/CU = -11%); 3 is neutral.
  __shared__ __align__(16) short sY[128 * ASTR];
  __shared__ __align__(16) short sH[128 * ASTR];      // hidden; prologue union:
                                                      //   shorts [0,2304)      = sTs sincos table
                                                      //   shorts [2304,12544)  = sC coord scratch
                                                      //   shorts [12544,12736) = sqbot/sqsub
  __shared__ __align__(16) short sW[GSH];             // staged weight group
  unsigned short* sTs = (unsigned short*)sH;
  short* sC    = sH + 2304;
  int*   sqbot = (int*)(sH + 12544);
  float* sqsub = (float*)(sH + 12544 + 96);

  const int t = threadIdx.x;
  const int blk = blockIdx.x;
  const int b = blk >> 11;
  const int qbase = (blk & 2047) * 16;
  const int lane = t & 63, wid = t >> 6;
  const int ln15 = lane & 15, quad = lane >> 4;
  const int rowb = wid * 32;
  const float* badj = (const float*)(ws + WTOT);

  // cooperative stage of weight group g into sW (linear 18,432B DMA, 1152 chunks)
  auto stageW = [&](int g) {
    const char* src = (const char*)ws + (size_t)g * (GSH * 2);
    char* dst = (char*)sW;
#pragma unroll
    for (int rr = 0; rr < 5; ++rr) {
      int idx = t + 256 * rr;                 // 16B chunk index, 1152 total
      if (rr < 4 || idx < 1152)
        gload_lds16(src + (size_t)idx * 16, dst + idx * 16);
    }
  };

  stageW(0);   // group 0 in flight under the whole prologue

  // ---- per-query setup (wave 0, 16 threads) ----
  if (t < 16) {
    float m[4][8];
    for (int i = 0; i < 4; ++i)
      for (int j = 0; j < 4; ++j) {
        m[i][j] = aff[b * 16 + i * 4 + j];
        m[i][j + 4] = (i == j) ? 1.f : 0.f;
      }
    for (int col = 0; col < 4; ++col) {
      int piv = col; float best = fabsf(m[col][col]);
      for (int rr = col + 1; rr < 4; ++rr) {
        float v = fabsf(m[rr][col]);
        if (v > best) { best = v; piv = rr; }
      }
      if (piv != col)
        for (int j = 0; j < 8; ++j) { float tmp = m[col][j]; m[col][j] = m[piv][j]; m[piv][j] = tmp; }
      float d = 1.f / m[col][col];
      for (int j = 0; j < 8; ++j) m[col][j] *= d;
      for (int rr = 0; rr < 4; ++rr) if (rr != col) {
        float f = m[rr][col];
        for (int j = 0; j < 8; ++j) m[rr][j] -= f * m[col][j];
      }
    }
    int qi = qbase + t;
    float x = qwc[((size_t)b * NQv + qi) * 3 + 0];
    float y = qwc[((size_t)b * NQv + qi) * 3 + 1];
    float z = qwc[((size_t)b * NQv + qi) * 3 + 2];
    float v0 = m[0][4] * x + m[0][5] * y + m[0][6] * z + m[0][7];
    float v1 = m[1][4] * x + m[1][5] * y + m[1][6] * z + m[1][7];
    float v2 = m[2][4] * x + m[2][5] * y + m[2][6] * z + m[2][7];
    int i0 = (int)floorf(v0), i1 = (int)floorf(v1), i2 = (int)floorf(v2);
    sqbot[t * 3 + 0] = i0; sqbot[t * 3 + 1] = i1; sqbot[t * 3 + 2] = i2;
    sqsub[t * 3 + 0] = v0 - (float)i0; sqsub[t * 3 + 1] = v1 - (float)i1; sqsub[t * 3 + 2] = v2 - (float)i2;
  }
  __syncthreads();

  // ---- per-wave sincos table: 144 tasks = 4q x 3d x 12fj (own slice of sTs) ----
#pragma unroll
  for (int i = 0; i < 3; ++i) {
    int u = lane + 64 * i;
    if (u < 144) {
      int ql = u / 36, rem = u - 36 * ql, d = rem / 12, fj = rem - 12 * d;
      int q = 4 * wid + ql;
      float sub = sqsub[q * 3 + d];
      float freq = exp2f((float)fj * 0.13208020839342968f);   // 3^(fj/12)
#pragma unroll
      for (int off = 0; off < 2; ++off) {
        float rel = (sub - (float)off + 1.f) * 0.5f;
        float ang = 6.283185307179586f * rel * freq;
        float sn, cs; __sincosf(ang, &sn, &cs);
        int base = ((q * 3 + d) * 2 + off) * 24 + fj;
        sTs[base]      = f2bfu(sn);
        sTs[base + 12] = f2bfu(cs);
      }
    }
  }
  // no barrier: sTs slice is wave-local

  // ---- wtri (register; read sqsub before it dies) ----
  float wtri = 0.f;
  if (lane < 32) {
    int row = rowb + lane;
    int ql = row >> 3, cor = row & 7;
    int oi = (cor >> 2) & 1, oj = (cor >> 1) & 1, ok = cor & 1;
    float wx = oi ? sqsub[ql * 3 + 0] : 1.f - sqsub[ql * 3 + 0];
    float wy = oj ? sqsub[ql * 3 + 1] : 1.f - sqsub[ql * 3 + 1];
    float wz = ok ? sqsub[ql * 3 + 2] : 1.f - sqsub[ql * 3 + 2];
    wtri = wx * wy * wz;
  }

  // ---- COORD plane build into sC (global rows, wave-disjoint), Bc preload ----
  {
    const int rl = lane >> 1;
    const int row = rowb + rl;
    const int ql = row >> 3, cor = row & 7;
    const int oi = (cor >> 2) & 1, oj = (cor >> 1) & 1, ok = cor & 1;
    int offv[3]; offv[0] = oi; offv[1] = oj; offv[2] = ok;
    const int cbase = (lane & 1) * 40;
    float qw3[3];
#pragma unroll
    for (int k = 0; k < 3; ++k)
      qw3[k] = qwc[((size_t)b * NQv + qbase + ql) * 3 + k];
#pragma unroll
    for (int g = 0; g < 10; ++g) {
      unsigned short hv[4];
#pragma unroll
      for (int r = 0; r < 4; ++r) {
        int ch = cbase + 4 * g + r;
        if (ch < 3) {
          float v = (float)clamp31(sqbot[ql * 3 + ch] + offv[ch]) - 15.5f;
          hv[r] = (unsigned short)(rnd16(v) >> 16);
        } else if (ch < 6) {
          float v = qw3[ch - 3] - 15.5f;
          hv[r] = (unsigned short)(rnd16(v) >> 16);
        } else if (ch < 78) {
          int i2 = ch - 6, d = i2 / 24, rr = i2 - 24 * d, sc = rr / 12, fj = rr - 12 * sc;
          hv[r] = sTs[(((ql * 3 + d) * 2 + offv[d]) * 2 + sc) * 12 + fj];
        } else hv[r] = 0;
      }
      *(uint2*)&sC[row * CSTR + cbase + 4 * g] =
          make_uint2((unsigned int)hv[0] | ((unsigned int)hv[1] << 16),
                     (unsigned int)hv[2] | ((unsigned int)hv[3] << 16));
    }
  }
  short8 Bc[3][2];
#pragma unroll
  for (int c = 0; c < 3; ++c)
#pragma unroll
    for (int nt = 0; nt < 2; ++nt)
      Bc[c][nt] = (c == 2 && quad >= 2)
                  ? (short8)0            // channels 80..95 are zero
                  : *(const short8*)&sC[(rowb + nt * 16 + ln15) * CSTR + c * 32 + quad * 8];

  // ---- feats -> sY rows ----
  {
    const int rl = lane >> 1;
    const int row = rowb + rl;
    const int ql = row >> 3, cor = row & 7;
    const int oi = (cor >> 2) & 1, oj = (cor >> 1) & 1, ok = cor & 1;
    const int jb = (lane & 1) * 48;
    const int ix = clamp31(sqbot[ql * 3 + 0] + oi);
    const int iy = clamp31(sqbot[ql * 3 + 1] + oj);
    const int iz = clamp31(sqbot[ql * 3 + 2] + ok);
    const int spat = (ix << 10) | (iy << 5) | iz;
    if (TRANSPOSED) {
      const unsigned short* src = ctxvt + ((size_t)(b << 15) + spat) * 96 + jb;
#pragma unroll
      for (int g = 0; g < 6; ++g)
        *(short8*)&sY[row * ASTR + jb + 8 * g] = *(const short8*)(src + 8 * g);
    } else {
#pragma unroll 4
      for (int g = 0; g < 12; ++g) {
        float vv[4];
#pragma unroll
        for (int r = 0; r < 4; ++r)
          vv[r] = ctxv[(((size_t)(b * 96 + jb + 4 * g + r)) << 15) + spat];
        *(uint2*)&sY[row * ASTR + jb + 4 * g] = make_uint2(pkp(vv[0], vv[1]), pkp(vv[2], vv[3]));
      }
    }
  }
  __syncthreads();   // drains vmcnt -> group 0 staged and visible

  auto epiH = [&](float4v (&C)[6][2]) {
#pragma unroll
    for (int mt = 0; mt < 6; ++mt)
#pragma unroll
      for (int nt = 0; nt < 2; ++nt) {
        int idx = (rowb + nt * 16 + ln15) * ASTR + mt * 16 + quad * 4;
        float4v c = C[mt][nt];
        float2v lo = {c[0], c[1]}, hi = {c[2], c[3]};
        float2v sl = silu2(lo), sh = silu2(hi);
        *(uint2*)&sH[idx] = make_uint2(pkbf(sl.x, sl.y), pkbf(sh.x, sh.y));
      }
  };
  auto epiSkip = [&](float4v (&C)[6][2]) {
#pragma unroll
    for (int mt = 0; mt < 6; ++mt)
#pragma unroll
      for (int nt = 0; nt < 2; ++nt) {
        int idx = (rowb + nt * 16 + ln15) * ASTR + mt * 16 + quad * 4;
        uint2 oh = *(uint2*)&sY[idx];
        float4v c = C[mt][nt];
        float2v lo = {c[0], c[1]}, hi = {c[2], c[3]};
        float2v y0, y1;
        y0.x = __uint_as_float(oh.x << 16);
        y0.y = __uint_as_float(oh.x & 0xffff0000u);
        y1.x = __uint_as_float(oh.y << 16);
        y1.y = __uint_as_float(oh.y & 0xffff0000u);
        y0 = y0 + silu2(lo);               // v_pk_add_f32
        y1 = y1 + silu2(hi);
        *(uint2*)&sY[idx] = make_uint2(pkbf(y0.x, y0.y), pkbf(y1.x, y1.y));
      }
  };

  // ---- round-3/7 verified schedule: compute | bar | stage+epi | bar | ... ----
  {
    float4v C[6][2];
    run_group<6, true , false>(sW, sY, Bc, badj,      96, C, lane, rowb);  // c0: L00 k0..95
    __syncthreads();
    stageW(1);
    __syncthreads();
    run_group<6, false, true >(sW, sY, Bc, badj,      96, C, lane, rowb);  // c1: L00 k96..191 (B=Bc)
    __syncthreads();
    stageW(2);
    epiH(C);                                                                // h(L00) -> sH
    __syncthreads();
    run_group<6, true , false>(sW, sH, Bc, b01,       96, C, lane, rowb);  // c2: L01
    __syncthreads();
    stageW(3);
    epiH(C);                                                                // h(L01) -> sH
    __syncthreads();
    run_group<6, true , false>(sW, sH, Bc, b02,       96, C, lane, rowb);  // c3: L02
    __syncthreads();
    stageW(4);
    epiSkip(C);                                                             // Y += silu(h) -> sY
    __syncthreads();
    run_group<6, true , false>(sW, sY, Bc, badj + 96, 96, C, lane, rowb);  // c4: L10 k0..95
    __syncthreads();
    stageW(5);
    __syncthreads();
    run_group<6, false, true >(sW, sY, Bc, badj,      96, C, lane, rowb);  // c5: L10 k96..191 (B=Bc)
    __syncthreads();
    stageW(6);
    epiH(C);                                                                // h(L10) -> sH
    __syncthreads();
    run_group<6, true , false>(sW, sH, Bc, b11,       96, C, lane, rowb);  // c6: L11
    __syncthreads();
    stageW(7);
    epiH(C);                                                                // h(L11) -> sH
    __syncthreads();
    run_group<6, true , false>(sW, sH, Bc, b12,       96, C, lane, rowb);  // c7: L12
    __syncthreads();
    stageW(8);
    epiSkip(C);                                                             // Y += silu(h) -> sY
    __syncthreads();
  }
  // ---- post layer + pred (f32 [row][52] view of sH) ----
  float* pred = (float*)sH;
  {
    float4v Cp[3][2];
    run_group<3, true, false>(sW, sY, Bc, bpost, 45, Cp, lane, rowb);      // c8: post (B=sY Y)
    float w0 = __shfl(wtri, ln15);          // wtri for row rowb + ln15
    float w1 = __shfl(wtri, 16 + ln15);     // wtri for row rowb + 16 + ln15
#pragma unroll
    for (int mt = 0; mt < 3; ++mt)
#pragma unroll
      for (int nt = 0; nt < 2; ++nt) {
        int row = rowb + nt * 16 + ln15, c0 = mt * 16 + quad * 4;
        float w = nt ? w1 : w0;
        float4v v = Cp[mt][nt];
        float2v lo = {v[0], v[1]}, hi = {v[2], v[3]};
        lo = lo * w;                        // v_pk_mul_f32
        hi = hi * w;
        float4v vs = {lo.x, lo.y, hi.x, hi.y};
        *(float4v*)&pred[row * 52 + c0] = vs;
      }
  }
  // ---- per-wave trilinear combine (queries wid*4..wid*4+3) + store ----
#pragma unroll
  for (int i = 0; i < 3; ++i) {
    int u = lane + 64 * i;
    if (u < 180) {
      int ql = u / 45, ch = u - ql * 45;
      float s = 0.f;
#pragma unroll
      for (int cor = 0; cor < 8; ++cor) s += pred[(rowb + ql * 8 + cor) * 52 + ch];
      out[(((size_t)(b * 45 + ch)) << 15) + qbase + wid * 4 + ql] = s;
    }
  }
}

extern "C" void kernel_launch(void* const* d_in, const int* in_sizes, int n_in,
                              void* d_out, int out_size, void* d_ws, size_t ws_size,
                              hipStream_t stream) {
  (void)in_sizes; (void)n_in; (void)out_size;
  const float* ctxv  = (const float*)d_in[0];
  const float* qwc   = (const float*)d_in[2];
  const float* aff   = (const float*)d_in[4];
  const float* w00   = (const float*)d_in[8];
  const float* b00   = (const float*)d_in[9];
  const float* w01   = (const float*)d_in[10];
  const float* b01   = (const float*)d_in[11];
  const float* w02   = (const float*)d_in[12];
  const float* b02   = (const float*)d_in[13];
  const float* w10   = (const float*)d_in[14];
  const float* b10   = (const float*)d_in[15];
  const float* w11   = (const float*)d_in[16];
  const float* b11   = (const float*)d_in[17];
  const float* w12   = (const float*)d_in[18];
  const float* b12   = (const float*)d_in[19];
  const float* wpost = (const float*)d_in[20];
  const float* bpost = (const float*)d_in[21];
  unsigned short* ws = (unsigned short*)d_ws;
  float* out = (float*)d_out;

  const size_t wbytes = (size_t)WTOT * sizeof(unsigned short) + 768;       // weight image + badj
  const size_t tbytes = (size_t)2 * 32768 * 96 * sizeof(unsigned short);   // bf16 ctxvt
  unsigned short* ctxvt = (unsigned short*)((char*)d_ws + wbytes);
  const bool useT = ws_size >= wbytes + tbytes;

  if (useT) {
    prep_kernel<<<dim3(WBLK + 1024), dim3(256), 0, stream>>>(
        ctxv, w00, w01, w02, w10, w11, w12, wpost, b00, b10, ws, ctxvt);
    decoder_kernel<true><<<dim3(4096), dim3(256), 0, stream>>>(
        ctxv, ctxvt, qwc, aff, b01, b02, b11, b12, bpost, ws, out);
  } else {
    prep_kernel<<<dim3(WBLK), dim3(256), 0, stream>>>(
        ctxv, w00, w01, w02, w10, w11, w12, wpost, b00, b10, ws, ctxvt);
    decoder_kernel<false><<<dim3(4096), dim3(256), 0, stream>>>(
        ctxv, ctxvt, qwc, aff, b01, b02, b11, b12, bpost, ws, out);
  }
}

// Round 13
// 277.010 us; speedup vs baseline: 1.0425x; 1.0425x over previous
//
#include <hip/hip_runtime.h>

#define NQv   32768
#define GSH   9216            // shorts per staged weight group: 18 tiles x 512
#define NGRP  9
#define WTOT  (GSH*NGRP)      // 82,944 shorts of weight image (324 blocks exactly)
#define ASTR  104             // feats/hidden plane stride in shorts (208B)
#define CSTR  80              // coord plane stride in shorts
#define WBLK  325             // prep weight blocks (324 weight + badj tail in block 324)

typedef __attribute__((ext_vector_type(8))) short  short8;
typedef __attribute__((ext_vector_type(4))) float  float4v;
typedef __attribute__((ext_vector_type(2))) float  float2v;

__device__ __forceinline__ float bfu2f(unsigned short u) {
  return __uint_as_float(((unsigned int)u) << 16);
}
__device__ __forceinline__ unsigned short f2bfu(float f) {
  unsigned int x = __float_as_uint(f);
  x += 0x7fffu + ((x >> 16) & 1u);   // RNE
  return (unsigned short)(x >> 16);
}
// ties-away bf16 round, result in bits [31:16]
__device__ __forceinline__ unsigned int rnd16(float f) {
  return __float_as_uint(f) + 0x8000u;
}
// pack two floats -> (bf16(hi)<<16)|bf16(lo) in 3 VALU (prologue paths)
__device__ __forceinline__ unsigned int pkp(float lo, float hi) {
  return __builtin_amdgcn_perm(rnd16(hi), rnd16(lo), 0x07060302u);
}
// single-instruction packed bf16 convert (RNE), src0->low — epilogue hot path
__device__ __forceinline__ unsigned int pkbf(float lo, float hi) {
  unsigned int r;
  asm("v_cvt_pk_bf16_f32 %0, %1, %2" : "=v"(r) : "v"(lo), "v"(hi));
  return r;
}
__device__ __forceinline__ float silu_f(float x) {
  float e = __expf(-x);
  return x * __builtin_amdgcn_rcpf(1.f + e);
}
// packed-pair silu: muls/adds become v_pk_*_f32 (VOP3P), trans stay scalar.
// Round-11 lesson: keep pairs INDEPENDENT (high ILP). rcp-sharing (silu4)
// lowered issue count but built a 10-deep serial chain and regressed 27%.
// Round-12 lesson: s_setprio around MFMA starves co-resident epilogue waves
// in this barrier-locked structure (-22%) — do not reapply.
__device__ __forceinline__ float2v silu2(float2v x) {
  float2v t = x * -1.44269504088896341f;     // v_pk_mul_f32
  float2v e;
  e.x = __builtin_amdgcn_exp2f(t.x);
  e.y = __builtin_amdgcn_exp2f(t.y);
  float2v s = e + 1.f;                       // v_pk_add_f32
  float2v r;
  r.x = __builtin_amdgcn_rcpf(s.x);
  r.y = __builtin_amdgcn_rcpf(s.y);
  return x * r;                              // v_pk_mul_f32
}
__device__ __forceinline__ int clamp31(int v) { return min(max(v, 0), 31); }

// async global->LDS, 16B per lane; LDS dest must be wave-uniform base + lane*16
__device__ __forceinline__ void gload_lds16(const void* g, void* l) {
  typedef const __attribute__((address_space(1))) unsigned int GU;
  typedef __attribute__((address_space(3))) unsigned int LU;
  __builtin_amdgcn_global_load_lds((GU*)g, (LU*)l, 16, 0, 0);
}

// ---- fused pre-kernel ----
// blocks [0,WBLK): build the weight image in CHUNK-LINEAR tile layout:
//   group g = 18 tiles (T = mt*3+cb), tile = 64 chunks (c = ln15*4+quad) of 8
//   shorts: ws[g*GSH + T*512 + c*8 + e] = W_g[k = cb*32+quad*8+e][n = mt*16+ln15].
//   A wave's ds_read_b128 for (mt,cb) then reads 64 CONSECUTIVE 16B chunks.
//   Plus centered-coord adjusted biases (badj, f32) at ws+WTOT.
// blocks [WBLK, WBLK+1024): transpose ctxv [b][c][spat] f32 -> ctxvt [b][spat][c] bf16.
__global__ __launch_bounds__(256) void prep_kernel(
    const float* __restrict__ ctxv,
    const float* __restrict__ w00, const float* __restrict__ w01,
    const float* __restrict__ w02, const float* __restrict__ w10,
    const float* __restrict__ w11, const float* __restrict__ w12,
    const float* __restrict__ wpost,
    const float* __restrict__ b00, const float* __restrict__ b10,
    unsigned short* __restrict__ ws, unsigned short* __restrict__ ctxvt)
{
  __shared__ float tile[96][65];
  const int blk0 = blockIdx.x;
  const int t = threadIdx.x;
  if (blk0 < WBLK) {
    int e = blk0 * 256 + t;
    if (e >= WTOT) {
      // badj: b' = b + 15.5*sum_{k=96..101} W[k][ch]  (coords centered by 15.5)
      int e2 = e - WTOT;
      if (e2 < 192) {
        int mat = e2 / 96, ch = e2 - mat * 96;
        const float* w = mat ? w10 : w00;
        const float* bb = mat ? b10 : b00;
        float s = bb[ch];
#pragma unroll
        for (int k = 0; k < 6; ++k) s += 15.5f * w[(96 + k) * 96 + ch];
        ((float*)(ws + WTOT))[e2] = s;
      }
      return;
    }
    int g = e / GSH, r = e - g * GSH;
    int T = r >> 9, c = (r >> 3) & 63, e8 = r & 7;
    int mt = T / 3, cb = T - mt * 3;
    int ln15 = c >> 2, quad = c & 3;
    int n = mt * 16 + ln15;
    int kk = cb * 32 + quad * 8 + e8;        // 0..95
    const float* src; int Ksrc, Nsrc, kofs;
    switch (g) {
      case 0:  src = w00;   Ksrc = 174; Nsrc = 96; kofs = 0;  break;
      case 1:  src = w00;   Ksrc = 174; Nsrc = 96; kofs = 96; break;
      case 2:  src = w01;   Ksrc = 96;  Nsrc = 96; kofs = 0;  break;
      case 3:  src = w02;   Ksrc = 96;  Nsrc = 96; kofs = 0;  break;
      case 4:  src = w10;   Ksrc = 174; Nsrc = 96; kofs = 0;  break;
      case 5:  src = w10;   Ksrc = 174; Nsrc = 96; kofs = 96; break;
      case 6:  src = w11;   Ksrc = 96;  Nsrc = 96; kofs = 0;  break;
      case 7:  src = w12;   Ksrc = 96;  Nsrc = 96; kofs = 0;  break;
      default: src = wpost; Ksrc = 96;  Nsrc = 45; kofs = 0;  break;
    }
    int k = kofs + kk;
    float v = (k < Ksrc && n < Nsrc) ? src[k * Nsrc + n] : 0.f;
    ws[e] = f2bfu(v);
    return;
  }
  const int blk = blk0 - WBLK;              // 1024 = 2 batches * 512
  const int b = blk >> 9, s0 = (blk & 511) << 6;
  const int cq = t >> 6, sl = t & 63;
#pragma unroll
  for (int p = 0; p < 24; ++p) {
    int c = cq + p * 4;
    tile[c][sl] = ctxv[(((size_t)(b * 96 + c)) << 15) + s0 + sl];
  }
  __syncthreads();
#pragma unroll
  for (int i = 0; i < 24; ++i) {
    int u = t + 256 * i;
    int s = u / 96, c = u - s * 96;
    ctxvt[((size_t)(b << 15) + s0 + s) * 96 + c] = f2bfu(tile[c][s]);
  }
}

// ---- group GEMM: one staged weight group (96 outs x 96 k) from LDS sW
//      (chunk-linear tiles);
//      B either LDS plane rows rowb.. (stride ASTR) or register coord frags Bin ----
template<int NM, bool INIT, bool BREG>
__device__ __forceinline__ void run_group(
    const short* __restrict__ sWp,
    const short* pA, const short8 (&Bin)[3][2],
    const float* __restrict__ bias, int biasN,
    float4v (&C)[NM][2], int lane, int rowb)
{
  const int ln15 = lane & 15, quad = lane >> 4;
  const int cidx = ((ln15 << 2) | quad) << 3;    // chunk offset in shorts
  if (INIT) {
    if (biasN >= NM * 16) {
#pragma unroll
      for (int mt = 0; mt < NM; ++mt) {
        float4v bv = *(const float4v*)(bias + mt * 16 + quad * 4);
        C[mt][0] = bv; C[mt][1] = bv;
      }
    } else {
#pragma unroll
      for (int mt = 0; mt < NM; ++mt) {
        int c0 = mt * 16 + quad * 4;
        float4v bv;
#pragma unroll
        for (int r = 0; r < 4; ++r) bv[r] = (c0 + r < biasN) ? bias[c0 + r] : 0.f;
        C[mt][0] = bv; C[mt][1] = bv;
      }
    }
  }
  short8 Wh[3][NM];
#pragma unroll
  for (int cb = 0; cb < 3; ++cb)
#pragma unroll
    for (int mt = 0; mt < NM; ++mt)
      Wh[cb][mt] = *(const short8*)&sWp[((mt * 3 + cb) << 9) + cidx];
  short8 Bh[3][2];
  if (BREG) {
#pragma unroll
    for (int cb = 0; cb < 3; ++cb) {
      Bh[cb][0] = Bin[cb][0]; Bh[cb][1] = Bin[cb][1];
    }
  } else {
#pragma unroll
    for (int cb = 0; cb < 3; ++cb)
#pragma unroll
      for (int nt = 0; nt < 2; ++nt)
        Bh[cb][nt] = *(const short8*)&pA[(rowb + nt * 16 + ln15) * ASTR + cb * 32 + quad * 8];
  }
#pragma unroll
  for (int cb = 0; cb < 3; ++cb)
#pragma unroll
    for (int mt = 0; mt < NM; ++mt)
#pragma unroll
      for (int nt = 0; nt < 2; ++nt)
        C[mt][nt] = __builtin_amdgcn_mfma_f32_16x16x32_bf16(Wh[cb][mt], Bh[cb][nt], C[mt][nt], 0, 0, 0);
}

template<bool TRANSPOSED>
__global__ __launch_bounds__(256, 2) void decoder_kernel(
    const float* __restrict__ ctxv,            // [2,96,32768] f32
    const unsigned short* __restrict__ ctxvt,  // [2,32768,96] bf16 (in ws) or unused
    const float* __restrict__ qwc,     // [2,32768,3]
    const float* __restrict__ aff,     // [2,4,4]
    const float* __restrict__ b01, const float* __restrict__ b02,
    const float* __restrict__ b11, const float* __restrict__ b12,
    const float* __restrict__ bpost,
    const unsigned short* __restrict__ ws,
    float* __restrict__ out)           // [2,45,32768]
{
  // LDS: sY 26,624 + sH 26,624 + sW 18,432 = 71,680 B -> 2 blocks/CU.
  // 2 blocks/CU is load-bearing (round-8: 1 block/CU = -11%); 3 is neutral.
  __shared__ __align__(16) short sY[128 * ASTR];
  __shared__ __align__(16) short sH[128 * ASTR];      // hidden; prologue union:
                                                      //   shorts [0,2304)      = sTs sincos table
                                                      //   shorts [2304,12544)  = sC coord scratch
                                                      //   shorts [12544,12736) = sqbot/sqsub
  __shared__ __align__(16) short sW[GSH];             // staged weight group
  unsigned short* sTs = (unsigned short*)sH;
  short* sC    = sH + 2304;
  int*   sqbot = (int*)(sH + 12544);
  float* sqsub = (float*)(sH + 12544 + 96);

  const int t = threadIdx.x;
  const int blk = blockIdx.x;
  const int b = blk >> 11;
  const int qbase = (blk & 2047) * 16;
  const int lane = t & 63, wid = t >> 6;
  const int ln15 = lane & 15, quad = lane >> 4;
  const int rowb = wid * 32;
  const float* badj = (const float*)(ws + WTOT);

  // cooperative stage of weight group g into sW (linear 18,432B DMA, 1152 chunks)
  auto stageW = [&](int g) {
    const char* src = (const char*)ws + (size_t)g * (GSH * 2);
    char* dst = (char*)sW;
#pragma unroll
    for (int rr = 0; rr < 5; ++rr) {
      int idx = t + 256 * rr;                 // 16B chunk index, 1152 total
      if (rr < 4 || idx < 1152)
        gload_lds16(src + (size_t)idx * 16, dst + idx * 16);
    }
  };

  stageW(0);   // group 0 in flight under the whole prologue

  // ---- per-query setup (wave 0, 16 threads) ----
  if (t < 16) {
    float m[4][8];
    for (int i = 0; i < 4; ++i)
      for (int j = 0; j < 4; ++j) {
        m[i][j] = aff[b * 16 + i * 4 + j];
        m[i][j + 4] = (i == j) ? 1.f : 0.f;
      }
    for (int col = 0; col < 4; ++col) {
      int piv = col; float best = fabsf(m[col][col]);
      for (int rr = col + 1; rr < 4; ++rr) {
        float v = fabsf(m[rr][col]);
        if (v > best) { best = v; piv = rr; }
      }
      if (piv != col)
        for (int j = 0; j < 8; ++j) { float tmp = m[col][j]; m[col][j] = m[piv][j]; m[piv][j] = tmp; }
      float d = 1.f / m[col][col];
      for (int j = 0; j < 8; ++j) m[col][j] *= d;
      for (int rr = 0; rr < 4; ++rr) if (rr != col) {
        float f = m[rr][col];
        for (int j = 0; j < 8; ++j) m[rr][j] -= f * m[col][j];
      }
    }
    int qi = qbase + t;
    float x = qwc[((size_t)b * NQv + qi) * 3 + 0];
    float y = qwc[((size_t)b * NQv + qi) * 3 + 1];
    float z = qwc[((size_t)b * NQv + qi) * 3 + 2];
    float v0 = m[0][4] * x + m[0][5] * y + m[0][6] * z + m[0][7];
    float v1 = m[1][4] * x + m[1][5] * y + m[1][6] * z + m[1][7];
    float v2 = m[2][4] * x + m[2][5] * y + m[2][6] * z + m[2][7];
    int i0 = (int)floorf(v0), i1 = (int)floorf(v1), i2 = (int)floorf(v2);
    sqbot[t * 3 + 0] = i0; sqbot[t * 3 + 1] = i1; sqbot[t * 3 + 2] = i2;
    sqsub[t * 3 + 0] = v0 - (float)i0; sqsub[t * 3 + 1] = v1 - (float)i1; sqsub[t * 3 + 2] = v2 - (float)i2;
  }
  __syncthreads();

  // ---- per-wave sincos table: 144 tasks = 4q x 3d x 12fj (own slice of sTs) ----
#pragma unroll
  for (int i = 0; i < 3; ++i) {
    int u = lane + 64 * i;
    if (u < 144) {
      int ql = u / 36, rem = u - 36 * ql, d = rem / 12, fj = rem - 12 * d;
      int q = 4 * wid + ql;
      float sub = sqsub[q * 3 + d];
      float freq = exp2f((float)fj * 0.13208020839342968f);   // 3^(fj/12)
#pragma unroll
      for (int off = 0; off < 2; ++off) {
        float rel = (sub - (float)off + 1.f) * 0.5f;
        float ang = 6.283185307179586f * rel * freq;
        float sn, cs; __sincosf(ang, &sn, &cs);
        int base = ((q * 3 + d) * 2 + off) * 24 + fj;
        sTs[base]      = f2bfu(sn);
        sTs[base + 12] = f2bfu(cs);
      }
    }
  }
  // no barrier: sTs slice is wave-local

  // ---- wtri (register; read sqsub before it dies) ----
  float wtri = 0.f;
  if (lane < 32) {
    int row = rowb + lane;
    int ql = row >> 3, cor = row & 7;
    int oi = (cor >> 2) & 1, oj = (cor >> 1) & 1, ok = cor & 1;
    float wx = oi ? sqsub[ql * 3 + 0] : 1.f - sqsub[ql * 3 + 0];
    float wy = oj ? sqsub[ql * 3 + 1] : 1.f - sqsub[ql * 3 + 1];
    float wz = ok ? sqsub[ql * 3 + 2] : 1.f - sqsub[ql * 3 + 2];
    wtri = wx * wy * wz;
  }

  // ---- COORD plane build into sC (global rows, wave-disjoint), Bc preload ----
  {
    const int rl = lane >> 1;
    const int row = rowb + rl;
    const int ql = row >> 3, cor = row & 7;
    const int oi = (cor >> 2) & 1, oj = (cor >> 1) & 1, ok = cor & 1;
    int offv[3]; offv[0] = oi; offv[1] = oj; offv[2] = ok;
    const int cbase = (lane & 1) * 40;
    float qw3[3];
#pragma unroll
    for (int k = 0; k < 3; ++k)
      qw3[k] = qwc[((size_t)b * NQv + qbase + ql) * 3 + k];
#pragma unroll
    for (int g = 0; g < 10; ++g) {
      unsigned short hv[4];
#pragma unroll
      for (int r = 0; r < 4; ++r) {
        int ch = cbase + 4 * g + r;
        if (ch < 3) {
          float v = (float)clamp31(sqbot[ql * 3 + ch] + offv[ch]) - 15.5f;
          hv[r] = (unsigned short)(rnd16(v) >> 16);
        } else if (ch < 6) {
          float v = qw3[ch - 3] - 15.5f;
          hv[r] = (unsigned short)(rnd16(v) >> 16);
        } else if (ch < 78) {
          int i2 = ch - 6, d = i2 / 24, rr = i2 - 24 * d, sc = rr / 12, fj = rr - 12 * sc;
          hv[r] = sTs[(((ql * 3 + d) * 2 + offv[d]) * 2 + sc) * 12 + fj];
        } else hv[r] = 0;
      }
      *(uint2*)&sC[row * CSTR + cbase + 4 * g] =
          make_uint2((unsigned int)hv[0] | ((unsigned int)hv[1] << 16),
                     (unsigned int)hv[2] | ((unsigned int)hv[3] << 16));
    }
  }
  short8 Bc[3][2];
#pragma unroll
  for (int c = 0; c < 3; ++c)
#pragma unroll
    for (int nt = 0; nt < 2; ++nt)
      Bc[c][nt] = (c == 2 && quad >= 2)
                  ? (short8)0            // channels 80..95 are zero
                  : *(const short8*)&sC[(rowb + nt * 16 + ln15) * CSTR + c * 32 + quad * 8];

  // ---- feats -> sY rows ----
  {
    const int rl = lane >> 1;
    const int row = rowb + rl;
    const int ql = row >> 3, cor = row & 7;
    const int oi = (cor >> 2) & 1, oj = (cor >> 1) & 1, ok = cor & 1;
    const int jb = (lane & 1) * 48;
    const int ix = clamp31(sqbot[ql * 3 + 0] + oi);
    const int iy = clamp31(sqbot[ql * 3 + 1] + oj);
    const int iz = clamp31(sqbot[ql * 3 + 2] + ok);
    const int spat = (ix << 10) | (iy << 5) | iz;
    if (TRANSPOSED) {
      const unsigned short* src = ctxvt + ((size_t)(b << 15) + spat) * 96 + jb;
#pragma unroll
      for (int g = 0; g < 6; ++g)
        *(short8*)&sY[row * ASTR + jb + 8 * g] = *(const short8*)(src + 8 * g);
    } else {
#pragma unroll 4
      for (int g = 0; g < 12; ++g) {
        float vv[4];
#pragma unroll
        for (int r = 0; r < 4; ++r)
          vv[r] = ctxv[(((size_t)(b * 96 + jb + 4 * g + r)) << 15) + spat];
        *(uint2*)&sY[row * ASTR + jb + 4 * g] = make_uint2(pkp(vv[0], vv[1]), pkp(vv[2], vv[3]));
      }
    }
  }
  __syncthreads();   // drains vmcnt -> group 0 staged and visible

  auto epiH = [&](float4v (&C)[6][2]) {
#pragma unroll
    for (int mt = 0; mt < 6; ++mt)
#pragma unroll
      for (int nt = 0; nt < 2; ++nt) {
        int idx = (rowb + nt * 16 + ln15) * ASTR + mt * 16 + quad * 4;
        float4v c = C[mt][nt];
        float2v lo = {c[0], c[1]}, hi = {c[2], c[3]};
        float2v sl = silu2(lo), sh = silu2(hi);
        *(uint2*)&sH[idx] = make_uint2(pkbf(sl.x, sl.y), pkbf(sh.x, sh.y));
      }
  };
  auto epiSkip = [&](float4v (&C)[6][2]) {
#pragma unroll
    for (int mt = 0; mt < 6; ++mt)
#pragma unroll
      for (int nt = 0; nt < 2; ++nt) {
        int idx = (rowb + nt * 16 + ln15) * ASTR + mt * 16 + quad * 4;
        uint2 oh = *(uint2*)&sY[idx];
        float4v c = C[mt][nt];
        float2v lo = {c[0], c[1]}, hi = {c[2], c[3]};
        float2v y0, y1;
        y0.x = __uint_as_float(oh.x << 16);
        y0.y = __uint_as_float(oh.x & 0xffff0000u);
        y1.x = __uint_as_float(oh.y << 16);
        y1.y = __uint_as_float(oh.y & 0xffff0000u);
        y0 = y0 + silu2(lo);               // v_pk_add_f32
        y1 = y1 + silu2(hi);
        *(uint2*)&sY[idx] = make_uint2(pkbf(y0.x, y0.y), pkbf(y1.x, y1.y));
      }
  };

  // ---- round-3/7 verified schedule: compute | bar | stage+epi | bar | ... ----
  {
    float4v C[6][2];
    run_group<6, true , false>(sW, sY, Bc, badj,      96, C, lane, rowb);  // c0: L00 k0..95
    __syncthreads();
    stageW(1);
    __syncthreads();
    run_group<6, false, true >(sW, sY, Bc, badj,      96, C, lane, rowb);  // c1: L00 k96..191 (B=Bc)
    __syncthreads();
    stageW(2);
    epiH(C);                                                                // h(L00) -> sH
    __syncthreads();
    run_group<6, true , false>(sW, sH, Bc, b01,       96, C, lane, rowb);  // c2: L01
    __syncthreads();
    stageW(3);
    epiH(C);                                                                // h(L01) -> sH
    __syncthreads();
    run_group<6, true , false>(sW, sH, Bc, b02,       96, C, lane, rowb);  // c3: L02
    __syncthreads();
    stageW(4);
    epiSkip(C);                                                             // Y += silu(h) -> sY
    __syncthreads();
    run_group<6, true , false>(sW, sY, Bc, badj + 96, 96, C, lane, rowb);  // c4: L10 k0..95
    __syncthreads();
    stageW(5);
    __syncthreads();
    run_group<6, false, true >(sW, sY, Bc, badj,      96, C, lane, rowb);  // c5: L10 k96..191 (B=Bc)
    __syncthreads();
    stageW(6);
    epiH(C);                                                                // h(L10) -> sH
    __syncthreads();
    run_group<6, true , false>(sW, sH, Bc, b11,       96, C, lane, rowb);  // c6: L11
    __syncthreads();
    stageW(7);
    epiH(C);                                                                // h(L11) -> sH
    __syncthreads();
    run_group<6, true , false>(sW, sH, Bc, b12,       96, C, lane, rowb);  // c7: L12
    __syncthreads();
    stageW(8);
    epiSkip(C);                                                             // Y += silu(h) -> sY
    __syncthreads();
  }
  // ---- post layer + pred (f32 [row][52] view of sH) ----
  float* pred = (float*)sH;
  {
    float4v Cp[3][2];
    run_group<3, true, false>(sW, sY, Bc, bpost, 45, Cp, lane, rowb);      // c8: post (B=sY Y)
    float w0 = __shfl(wtri, ln15);          // wtri for row rowb + ln15
    float w1 = __shfl(wtri, 16 + ln15);     // wtri for row rowb + 16 + ln15
#pragma unroll
    for (int mt = 0; mt < 3; ++mt)
#pragma unroll
      for (int nt = 0; nt < 2; ++nt) {
        int row = rowb + nt * 16 + ln15, c0 = mt * 16 + quad * 4;
        float w = nt ? w1 : w0;
        float4v v = Cp[mt][nt];
        float2v lo = {v[0], v[1]}, hi = {v[2], v[3]};
        lo = lo * w;                        // v_pk_mul_f32
        hi = hi * w;
        float4v vs = {lo.x, lo.y, hi.x, hi.y};
        *(float4v*)&pred[row * 52 + c0] = vs;
      }
  }
  // ---- per-wave trilinear combine (queries wid*4..wid*4+3) + store ----
#pragma unroll
  for (int i = 0; i < 3; ++i) {
    int u = lane + 64 * i;
    if (u < 180) {
      int ql = u / 45, ch = u - ql * 45;
      float s = 0.f;
#pragma unroll
      for (int cor = 0; cor < 8; ++cor) s += pred[(rowb + ql * 8 + cor) * 52 + ch];
      out[(((size_t)(b * 45 + ch)) << 15) + qbase + wid * 4 + ql] = s;
    }
  }
}

extern "C" void kernel_launch(void* const* d_in, const int* in_sizes, int n_in,
                              void* d_out, int out_size, void* d_ws, size_t ws_size,
                              hipStream_t stream) {
  (void)in_sizes; (void)n_in; (void)out_size;
  const float* ctxv  = (const float*)d_in[0];
  const float* qwc   = (const float*)d_in[2];
  const float* aff   = (const float*)d_in[4];
  const float* w00   = (const float*)d_in[8];
  const float* b00   = (const float*)d_in[9];
  const float* w01   = (const float*)d_in[10];
  const float* b01   = (const float*)d_in[11];
  const float* w02   = (const float*)d_in[12];
  const float* b02   = (const float*)d_in[13];
  const float* w10   = (const float*)d_in[14];
  const float* b10   = (const float*)d_in[15];
  const float* w11   = (const float*)d_in[16];
  const float* b11   = (const float*)d_in[17];
  const float* w12   = (const float*)d_in[18];
  const float* b12   = (const float*)d_in[19];
  const float* wpost = (const float*)d_in[20];
  const float* bpost = (const float*)d_in[21];
  unsigned short* ws = (unsigned short*)d_ws;
  float* out = (float*)d_out;

  const size_t wbytes = (size_t)WTOT * sizeof(unsigned short) + 768;       // weight image + badj
  const size_t tbytes = (size_t)2 * 32768 * 96 * sizeof(unsigned short);   // bf16 ctxvt
  unsigned short* ctxvt = (unsigned short*)((char*)d_ws + wbytes);
  const bool useT = ws_size >= wbytes + tbytes;

  if (useT) {
    prep_kernel<<<dim3(WBLK + 1024), dim3(256), 0, stream>>>(
        ctxv, w00, w01, w02, w10, w11, w12, wpost, b00, b10, ws, ctxvt);
    decoder_kernel<true><<<dim3(4096), dim3(256), 0, stream>>>(
        ctxv, ctxvt, qwc, aff, b01, b02, b11, b12, bpost, ws, out);
  } else {
    prep_kernel<<<dim3(WBLK), dim3(256), 0, stream>>>(
        ctxv, w00, w01, w02, w10, w11, w12, wpost, b00, b10, ws, ctxvt);
    decoder_kernel<false><<<dim3(4096), dim3(256), 0, stream>>>(
        ctxv, ctxvt, qwc, aff, b01, b02, b11, b12, bpost, ws, out);
  }
}